// Round 5
// baseline (4325.960 us; speedup 1.0000x reference)
//
#include <hip/hip_runtime.h>
#include <hip/hip_bf16.h>
#include <stdint.h>
#include <stddef.h>

// Problem dims: B=1024, T=512, F=8, E=16, H=32, O=1, TO=24

#define LOG2E 1.44269504088896340736f

__device__ __forceinline__ float fast_sigmoid(float x){
    return __builtin_amdgcn_rcpf(1.f + __builtin_amdgcn_exp2f(-LOG2E * x));
}
__device__ __forceinline__ float fast_tanh(float x){
    return 1.f - 2.f * __builtin_amdgcn_rcpf(1.f + __builtin_amdgcn_exp2f(2.f * LOG2E * x));
}
__device__ __forceinline__ float bflo(unsigned u){ return __uint_as_float(u << 16); }
__device__ __forceinline__ float bfhi(unsigned u){ return __uint_as_float(u & 0xffff0000u); }
__device__ __forceinline__ float bperm(int addr, float v){
    return __int_as_float(__builtin_amdgcn_ds_bpermute(addr, __float_as_int(v)));
}

// ---------------------------------------------------------------------------
// Software grid barrier, contention-safe design:
//  - hierarchical arrival: 8 sub-counters (one 64B line each, indexed
//    blockIdx&7 == XCD on round-robin dispatch) -> master counter -> flag
//  - waiters poll the flag with READ-ONLY atomic loads (no RMW ping-pong)
//  - one fresh (counters,flag) set per barrier instance; zeroed beforehand
// Instance layout: 10 cache lines = 160 words (8 sub @ +16*i, master @ +128,
// flag @ +144). 48 instances = 30720 B.
// ---------------------------------------------------------------------------
#define GBAR_STRIDE 160
#define GBAR_WORDS  (48 * GBAR_STRIDE)

__device__ __forceinline__ void gbar(unsigned* base, int inst){
    __syncthreads();
    if (threadIdx.x == 0){
        unsigned* ib = base + inst * GBAR_STRIDE;
        __threadfence();                              // release my writes
        unsigned sub = blockIdx.x & 7u;
        unsigned old = __hip_atomic_fetch_add(ib + sub * 16, 1u,
                          __ATOMIC_ACQ_REL, __HIP_MEMORY_SCOPE_AGENT);
        if (old == 63u){                              // last of my 64-block subgroup
            unsigned m = __hip_atomic_fetch_add(ib + 128, 1u,
                            __ATOMIC_ACQ_REL, __HIP_MEMORY_SCOPE_AGENT);
            if (m == 7u)                              // last subgroup overall
                __hip_atomic_store(ib + 144, 1u,
                                   __ATOMIC_RELEASE, __HIP_MEMORY_SCOPE_AGENT);
        }
        unsigned spins = 0;
        while (__hip_atomic_load(ib + 144, __ATOMIC_ACQUIRE,
                                 __HIP_MEMORY_SCOPE_AGENT) == 0u
               && spins < 400000u){                   // bounded: no infinite hang
            __builtin_amdgcn_s_sleep(8);
            ++spins;
        }
        __threadfence();                              // acquire remote writes
    }
    __syncthreads();
}

// ---------------------------------------------------------------------------
// Encoder: bidirectional GRU, one wave per sequence (64 lanes; lane = (j, K-half)).
// grid 512 x 256.
// ---------------------------------------------------------------------------
__global__ __launch_bounds__(256, 2) void enc_kernel(
    const float* __restrict__ x,
    const float* __restrict__ emb_w, const float* __restrict__ emb_b,
    const float* __restrict__ wih_f, const float* __restrict__ whh_f,
    const float* __restrict__ bih_f, const float* __restrict__ bhh_f,
    const float* __restrict__ wih_b, const float* __restrict__ whh_b,
    const float* __restrict__ bih_b, const float* __restrict__ bhh_b,
    __hip_bfloat16* __restrict__ enc_outT, float* __restrict__ hT)
{
    int tid = threadIdx.x;
    int l = tid & 63;
    int wv = tid >> 6;
    int j = l & 31;
    int p = l >> 5;
    int S = blockIdx.x * 4 + wv;        // 0..2047
    int dir = S >> 10;
    int b = S & 1023;
    const float* wih = dir ? wih_b : wih_f;
    const float* whh = dir ? whh_b : whh_f;
    const float* bih = dir ? bih_b : bih_f;
    const float* bhh = dir ? bhh_b : bhh_f;

    float wr[8], wz[8], wn[8];
#pragma unroll
    for (int e = 0; e < 8; e++){
        int ee = 8 * p + e;
        wr[e] = wih[j * 16 + ee];
        wz[e] = wih[(32 + j) * 16 + ee];
        wn[e] = wih[(64 + j) * 16 + ee];
    }
    float ur[16], uz[16], un[16];
#pragma unroll
    for (int k = 0; k < 16; k++){
        int kk = 16 * p + k;
        ur[k] = whh[j * 32 + kk];
        uz[k] = whh[(32 + j) * 32 + kk];
        un[k] = whh[(64 + j) * 32 + kk];
    }
    float c_r  = p ? 0.f : (bih[j] + bhh[j]);
    float c_z  = p ? 0.f : (bih[32 + j] + bhh[32 + j]);
    float c_ni = p ? 0.f : bih[64 + j];
    float c_nh = p ? 0.f : bhh[64 + j];

    float ew[8];
#pragma unroll
    for (int f = 0; f < 8; f++) ew[f] = emb_w[(l & 15) * 8 + f];
    float ebias = emb_b[l & 15];

    int aE[8], aH[16];
#pragma unroll
    for (int i = 0; i < 8; i++) aE[i] = 4 * (8 * p + i);
#pragma unroll
    for (int i = 0; i < 16; i++) aH[i] = 4 * (16 * p + i);
    int aX = 4 * (l ^ 32);

    float h = 0.f;
    const float* xp = x + (size_t)b * 4096 + (dir ? 511 * 8 : 0);
    __hip_bfloat16* op = enc_outT + ((size_t)b * 512 + (dir ? 511 : 0)) * 64 + dir * 32 + j;
    int xstep = dir ? -8 : 8;
    ptrdiff_t ostep = dir ? -64 : 64;

    float4 cx0 = ((const float4*)xp)[0];
    float4 cx1 = ((const float4*)xp)[1];

    for (int it = 0; it < 512; ++it){
        const float* np = (it == 511) ? xp : (xp + xstep);
        float4 nx0 = ((const float4*)np)[0];
        float4 nx1 = ((const float4*)np)[1];

        float e0 = ebias;
        e0 = fmaf(cx0.x, ew[0], e0); e0 = fmaf(cx0.y, ew[1], e0);
        e0 = fmaf(cx0.z, ew[2], e0); e0 = fmaf(cx0.w, ew[3], e0);
        e0 = fmaf(cx1.x, ew[4], e0); e0 = fmaf(cx1.y, ew[5], e0);
        e0 = fmaf(cx1.z, ew[6], e0); e0 = fmaf(cx1.w, ew[7], e0);
        float me = fmaxf(e0, 0.f);

        float Ar = c_r, Az = c_z, Ani = c_ni, Anh = c_nh;
#pragma unroll
        for (int i = 0; i < 8; i++){
            float ev = bperm(aE[i], me);
            Ar = fmaf(ev, wr[i], Ar);
            Az = fmaf(ev, wz[i], Az);
            Ani = fmaf(ev, wn[i], Ani);
        }
#pragma unroll
        for (int i = 0; i < 16; i++){
            float hk = bperm(aH[i], h);
            Ar = fmaf(hk, ur[i], Ar);
            Az = fmaf(hk, uz[i], Az);
            Anh = fmaf(hk, un[i], Anh);
        }
        Ar  += bperm(aX, Ar);
        Az  += bperm(aX, Az);
        Ani += bperm(aX, Ani);
        Anh += bperm(aX, Anh);

        float r = fast_sigmoid(Ar);
        float z = fast_sigmoid(Az);
        float cand = fast_tanh(fmaf(r, Anh, Ani));
        h = (1.f - z) * cand + z * h;

        *op = __float2bfloat16(h);
        cx0 = nx0; cx1 = nx1;
        xp = np; op += ostep;
    }
    hT[b * 64 + dir * 32 + j] = h;
}

// ---------------------------------------------------------------------------
// s0 / sWs0 / dec_in0 init + zero all barrier instances. grid 128 x 256.
// ---------------------------------------------------------------------------
__global__ __launch_bounds__(256) void s0_kernel(
    const float* __restrict__ hT, const float* __restrict__ act_w, const float* __restrict__ act_b,
    const float* __restrict__ attn_w, const float* __restrict__ x,
    float* __restrict__ s, float* __restrict__ sWs, float* __restrict__ dec_in,
    unsigned* __restrict__ bar)
{
    if (blockIdx.x == 0){
        for (int i = threadIdx.x; i < GBAR_WORDS; i += 256) bar[i] = 0u;
    }
    int j = threadIdx.x & 31, g = threadIdx.x >> 5;
    int b = blockIdx.x * 8 + g;
    float acc = act_b[j];
    const float4* aw = (const float4*)(act_w + j * 64);
    const float4* hp = (const float4*)(hT + b * 64);
#pragma unroll
    for (int c = 0; c < 16; c++){
        float4 wv = aw[c]; float4 hv = hp[c];
        acc = fmaf(hv.x, wv.x, acc); acc = fmaf(hv.y, wv.y, acc);
        acc = fmaf(hv.z, wv.z, acc); acc = fmaf(hv.w, wv.w, acc);
    }
    float s0v = fast_tanh(acc);
    s[b * 32 + j] = s0v;
    __shared__ float ssh[8][33];
    ssh[g][j] = s0v;
    __syncthreads();
    float a = 0.f;
    const float4* wsp = (const float4*)(attn_w + j * 96);   // Ws = attn_w[:, :32]
#pragma unroll
    for (int c = 0; c < 8; c++){
        float4 wv = wsp[c];
        a = fmaf(ssh[g][4 * c + 0], wv.x, a);
        a = fmaf(ssh[g][4 * c + 1], wv.y, a);
        a = fmaf(ssh[g][4 * c + 2], wv.z, a);
        a = fmaf(ssh[g][4 * c + 3], wv.w, a);
    }
    sWs[b * 32 + j] = a;
    if (j == 0) dec_in[b] = x[(size_t)b * 4096 + 511 * 8];
}

// ---------------------------------------------------------------------------
// enc_proj[t,b,j] = sum_d enc_outT[b,t,d] * We[j,d];  writes proj [t][b][32].
// grid 2048 x 256.
// ---------------------------------------------------------------------------
__global__ __launch_bounds__(256) void proj_kernel(
    const __hip_bfloat16* __restrict__ enc_outT, const float* __restrict__ attn_w,
    __hip_bfloat16* __restrict__ proj)
{
    int j = threadIdx.x & 31, g = threadIdx.x >> 5;
    float w[64];
    const float4* aw = (const float4*)(attn_w + j * 96 + 32);
#pragma unroll
    for (int c = 0; c < 16; c++){
        float4 q = aw[c];
        w[4 * c] = q.x; w[4 * c + 1] = q.y; w[4 * c + 2] = q.z; w[4 * c + 3] = q.w;
    }
    size_t base = (size_t)blockIdx.x * 256 + g * 32;
    for (int r = 0; r < 32; ++r){
        size_t pl = base + r;                      // pl = b*512 + t
        const uint4* ev = (const uint4*)(enc_outT + pl * 64);
        float acc = 0.f;
#pragma unroll
        for (int c = 0; c < 8; c++){
            uint4 pk = ev[c];
            acc = fmaf(bflo(pk.x), w[8 * c + 0], acc);
            acc = fmaf(bfhi(pk.x), w[8 * c + 1], acc);
            acc = fmaf(bflo(pk.y), w[8 * c + 2], acc);
            acc = fmaf(bfhi(pk.y), w[8 * c + 3], acc);
            acc = fmaf(bflo(pk.z), w[8 * c + 4], acc);
            acc = fmaf(bfhi(pk.z), w[8 * c + 5], acc);
            acc = fmaf(bflo(pk.w), w[8 * c + 6], acc);
            acc = fmaf(bfhi(pk.w), w[8 * c + 7], acc);
        }
        int t = (int)(pl & 511);
        int bb = (int)(pl >> 9);
        proj[((size_t)t * 1024 + bb) * 32 + j] = __float2bfloat16(acc);
    }
}

// ---------------------------------------------------------------------------
// Fused decoder: all 24 steps in ONE dispatch, grid 512 x 256 (2 blocks/CU).
// Per step: Phase A (block g = t): scores E[t,b], denom[t].  gbar
//           Phase C (block g -> b in {g, g+512}): softmax, ctx, GRU, fc. gbar
// ---------------------------------------------------------------------------
__global__ __launch_bounds__(256, 2) void dec_fused(
    const __hip_bfloat16* __restrict__ enc_outT, const __hip_bfloat16* __restrict__ proj,
    float* __restrict__ Ebuf, float* __restrict__ denom,
    float* __restrict__ s, float* __restrict__ sWs, float* __restrict__ dec_in,
    const float* __restrict__ demb_w, const float* __restrict__ demb_b,
    const float* __restrict__ dwih, const float* __restrict__ dwhh,
    const float* __restrict__ dbih, const float* __restrict__ dbhh,
    const float* __restrict__ attn_w, const float* __restrict__ attn_v,
    const float* __restrict__ fc_w, const float* __restrict__ fc_b,
    float* __restrict__ out, unsigned* __restrict__ bar)
{
    int tid = threadIdx.x;
    int g = blockIdx.x;
    int wv = tid >> 6, l = tid & 63;

    __shared__ float w_sh[512];
    __shared__ float redsh[4];
    __shared__ float ctxp[4][64];
    __shared__ float rnn_sh[80];    // [embd(16), ctx(64)]
    __shared__ float scur[32];
    __shared__ float gsum[64];
    __shared__ float gin[32], ghn[32];
    __shared__ float snew[32];

    for (int st = 0; st < 24; ++st){
        // ---------------- Phase A: scores for t = g ----------------
        {
            int t = g;
            float part = 0.f;
#pragma unroll
            for (int half = 0; half < 4; ++half){
                int b = half * 256 + tid;
                const uint4* pp = (const uint4*)(proj + ((size_t)t * 1024 + b) * 32);
                const float4* sp = (const float4*)(sWs + b * 32);
                float acc = 0.f;
#pragma unroll
                for (int c = 0; c < 4; c++){
                    uint4 pk = pp[c];
                    float4 s0 = sp[2 * c], s1 = sp[2 * c + 1];
                    acc = fmaf(attn_v[8 * c + 0], fast_tanh(s0.x + bflo(pk.x)), acc);
                    acc = fmaf(attn_v[8 * c + 1], fast_tanh(s0.y + bfhi(pk.x)), acc);
                    acc = fmaf(attn_v[8 * c + 2], fast_tanh(s0.z + bflo(pk.y)), acc);
                    acc = fmaf(attn_v[8 * c + 3], fast_tanh(s0.w + bfhi(pk.y)), acc);
                    acc = fmaf(attn_v[8 * c + 4], fast_tanh(s1.x + bflo(pk.z)), acc);
                    acc = fmaf(attn_v[8 * c + 5], fast_tanh(s1.y + bfhi(pk.z)), acc);
                    acc = fmaf(attn_v[8 * c + 6], fast_tanh(s1.z + bflo(pk.w)), acc);
                    acc = fmaf(attn_v[8 * c + 7], fast_tanh(s1.w + bfhi(pk.w)), acc);
                }
                float Ev = __builtin_amdgcn_exp2f(LOG2E * acc);
                Ebuf[(size_t)t * 1024 + b] = Ev;
                part += Ev;
            }
#pragma unroll
            for (int o = 32; o >= 1; o >>= 1) part += __shfl_xor(part, o, 64);
            if (l == 0) redsh[wv] = part;
            __syncthreads();
            if (tid == 0) denom[t] = redsh[0] + redsh[1] + redsh[2] + redsh[3];
        }
        gbar(bar, 2 * st);

        // ---------------- Phase C: ctx + GRU for b = g, g+512 ----------------
        float inv0 = __builtin_amdgcn_rcpf(denom[tid]);
        float inv1 = __builtin_amdgcn_rcpf(denom[tid + 256]);
        for (int bb = 0; bb < 2; ++bb){
            int b = g + bb * 512;
            __syncthreads();
            w_sh[tid] = Ebuf[(size_t)tid * 1024 + b] * inv0;
            w_sh[tid + 256] = Ebuf[(size_t)(tid + 256) * 1024 + b] * inv1;
            if (tid < 16) rnn_sh[tid] = fmaxf(fmaf(dec_in[b], demb_w[tid], demb_b[tid]), 0.f);
            if (tid >= 32 && tid < 64) scur[tid - 32] = s[b * 32 + tid - 32];
            __syncthreads();

            float acc0 = 0.f, acc1 = 0.f, acc2 = 0.f, acc3 = 0.f;
            float acc4 = 0.f, acc5 = 0.f, acc6 = 0.f, acc7 = 0.f;
            const uint4* ep = (const uint4*)(enc_outT + (size_t)b * 32768);
#pragma unroll
            for (int i = 0; i < 16; i++){
                int idx = i * 256 + tid;
                uint4 pk = ep[idx];
                float wgt = w_sh[idx >> 3];
                acc0 = fmaf(wgt, bflo(pk.x), acc0);
                acc1 = fmaf(wgt, bfhi(pk.x), acc1);
                acc2 = fmaf(wgt, bflo(pk.y), acc2);
                acc3 = fmaf(wgt, bfhi(pk.y), acc3);
                acc4 = fmaf(wgt, bflo(pk.z), acc4);
                acc5 = fmaf(wgt, bfhi(pk.z), acc5);
                acc6 = fmaf(wgt, bflo(pk.w), acc6);
                acc7 = fmaf(wgt, bfhi(pk.w), acc7);
            }
#pragma unroll
            for (int o = 8; o <= 32; o <<= 1){
                acc0 += __shfl_xor(acc0, o, 64); acc1 += __shfl_xor(acc1, o, 64);
                acc2 += __shfl_xor(acc2, o, 64); acc3 += __shfl_xor(acc3, o, 64);
                acc4 += __shfl_xor(acc4, o, 64); acc5 += __shfl_xor(acc5, o, 64);
                acc6 += __shfl_xor(acc6, o, 64); acc7 += __shfl_xor(acc7, o, 64);
            }
            if (l < 8){
                float* cp = &ctxp[wv][l * 8];
                cp[0] = acc0; cp[1] = acc1; cp[2] = acc2; cp[3] = acc3;
                cp[4] = acc4; cp[5] = acc5; cp[6] = acc6; cp[7] = acc7;
            }
            __syncthreads();
            if (tid < 64) rnn_sh[16 + tid] = ctxp[0][tid] + ctxp[1][tid] + ctxp[2][tid] + ctxp[3][tid];
            __syncthreads();

            if (tid < 96){
                int row = tid;
                float gi = dbih[row];
                const float4* wr = (const float4*)(dwih + row * 80);
#pragma unroll
                for (int c = 0; c < 20; c++){
                    float4 wv4 = wr[c];
                    gi = fmaf(rnn_sh[4 * c + 0], wv4.x, gi);
                    gi = fmaf(rnn_sh[4 * c + 1], wv4.y, gi);
                    gi = fmaf(rnn_sh[4 * c + 2], wv4.z, gi);
                    gi = fmaf(rnn_sh[4 * c + 3], wv4.w, gi);
                }
                float gh = dbhh[row];
                const float4* urow = (const float4*)(dwhh + row * 32);
#pragma unroll
                for (int c = 0; c < 8; c++){
                    float4 wv4 = urow[c];
                    gh = fmaf(scur[4 * c + 0], wv4.x, gh);
                    gh = fmaf(scur[4 * c + 1], wv4.y, gh);
                    gh = fmaf(scur[4 * c + 2], wv4.z, gh);
                    gh = fmaf(scur[4 * c + 3], wv4.w, gh);
                }
                if (row < 64) gsum[row] = gi + gh;
                else { gin[row - 64] = gi; ghn[row - 64] = gh; }
            }
            __syncthreads();

            if (tid < 32){
                float r = fast_sigmoid(gsum[tid]);
                float z = fast_sigmoid(gsum[32 + tid]);
                float cand = fast_tanh(fmaf(r, ghn[tid], gin[tid]));
                float sn = (1.f - z) * cand + z * scur[tid];
                snew[tid] = sn;
                s[b * 32 + tid] = sn;
            }
            __syncthreads();

            if (tid < 32){   // next-step sWs
                float a = 0.f;
                const float4* aw = (const float4*)(attn_w + tid * 96);
#pragma unroll
                for (int c = 0; c < 8; c++){
                    float4 wv4 = aw[c];
                    a = fmaf(snew[4 * c + 0], wv4.x, a);
                    a = fmaf(snew[4 * c + 1], wv4.y, a);
                    a = fmaf(snew[4 * c + 2], wv4.z, a);
                    a = fmaf(snew[4 * c + 3], wv4.w, a);
                }
                sWs[b * 32 + tid] = a;
            } else if (tid >= 64 && tid < 128){   // fc
                int ll = tid - 64;
                float cv0 = (ll < 32) ? snew[ll] : rnn_sh[ll - 16];
                float p = cv0 * fc_w[ll];
                if (ll < 48){
                    int i = 64 + ll;
                    float cv1 = (i < 96) ? rnn_sh[i - 16] : rnn_sh[i - 96];
                    p = fmaf(cv1, fc_w[i], p);
                }
#pragma unroll
                for (int o = 32; o >= 1; o >>= 1) p += __shfl_xor(p, o, 64);
                if (ll == 0){
                    float pred = p + fc_b[0];
                    out[b * 24 + st] = pred;
                    dec_in[b] = pred;
                }
            }
        }
        gbar(bar, 2 * st + 1);
    }
}

// ---------------------------------------------------------------------------
extern "C" void kernel_launch(void* const* d_in, const int* in_sizes, int n_in,
                              void* d_out, int out_size, void* d_ws, size_t ws_size,
                              hipStream_t stream)
{
    const float* x      = (const float*)d_in[0];
    const float* emb_w  = (const float*)d_in[2];
    const float* emb_b  = (const float*)d_in[3];
    const float* wih_f  = (const float*)d_in[4];
    const float* whh_f  = (const float*)d_in[5];
    const float* bih_f  = (const float*)d_in[6];
    const float* bhh_f  = (const float*)d_in[7];
    const float* wih_b  = (const float*)d_in[8];
    const float* whh_b  = (const float*)d_in[9];
    const float* bih_b  = (const float*)d_in[10];
    const float* bhh_b  = (const float*)d_in[11];
    const float* act_w  = (const float*)d_in[12];
    const float* act_b  = (const float*)d_in[13];
    const float* attn_w = (const float*)d_in[14];
    const float* attn_v = (const float*)d_in[15];
    const float* demb_w = (const float*)d_in[16];
    const float* demb_b = (const float*)d_in[17];
    const float* dwih   = (const float*)d_in[18];
    const float* dwhh   = (const float*)d_in[19];
    const float* dbih   = (const float*)d_in[20];
    const float* dbhh   = (const float*)d_in[21];
    const float* fc_w   = (const float*)d_in[22];
    const float* fc_b   = (const float*)d_in[23];
    (void)in_sizes; (void)n_in; (void)out_size; (void)ws_size;

    char* w = (char*)d_ws;
    __hip_bfloat16* enc_outT = (__hip_bfloat16*)w;                // [b][t][64] bf16, 67108864 B
    __hip_bfloat16* proj     = (__hip_bfloat16*)(w + 67108864);   // [t][b][32] bf16, 33554432 B
    float* hT     = (float*)(w + 100663296);                      // 1024*64*4
    float* s      = (float*)(w + 100925440);                      // 1024*32*4
    float* sWs    = (float*)(w + 101056512);                      // 1024*32*4
    float* Ebuf   = (float*)(w + 101187584);                      // [t][b] f32, 2097152 B
    float* denom  = (float*)(w + 103284736);                      // 512*4
    unsigned* bar = (unsigned*)(w + 103286784);                   // 48*160*4 = 30720 B
    float* dec_in = (float*)(w + 103333888);                      // 1024*4
    float* out = (float*)d_out;

    enc_kernel<<<512, 256, 0, stream>>>(x, emb_w, emb_b, wih_f, whh_f, bih_f, bhh_f,
                                        wih_b, whh_b, bih_b, bhh_b, enc_outT, hT);
    s0_kernel<<<128, 256, 0, stream>>>(hT, act_w, act_b, attn_w, x, s, sWs, dec_in, bar);
    proj_kernel<<<2048, 256, 0, stream>>>(enc_outT, attn_w, proj);
    dec_fused<<<512, 256, 0, stream>>>(enc_outT, proj, Ebuf, denom, s, sWs, dec_in,
                                       demb_w, demb_b, dwih, dwhh, dbih, dbhh,
                                       attn_w, attn_v, fc_w, fc_b, out, bar);
}

// Round 6
// 1523.831 us; speedup vs baseline: 2.8389x; 2.8389x over previous
//
#include <hip/hip_runtime.h>
#include <hip/hip_bf16.h>
#include <stdint.h>
#include <stddef.h>

// Problem dims: B=1024, T=512, F=8, E=16, H=32, O=1, TO=24

#define LOG2E 1.44269504088896340736f

typedef float f4 __attribute__((ext_vector_type(4)));

__device__ __forceinline__ float fast_sigmoid(float x){
    return __builtin_amdgcn_rcpf(1.f + __builtin_amdgcn_exp2f(-LOG2E * x));
}
__device__ __forceinline__ float fast_tanh(float x){
    return 1.f - 2.f * __builtin_amdgcn_rcpf(1.f + __builtin_amdgcn_exp2f(2.f * LOG2E * x));
}
__device__ __forceinline__ float bflo(unsigned u){ return __uint_as_float(u << 16); }
__device__ __forceinline__ float bfhi(unsigned u){ return __uint_as_float(u & 0xffff0000u); }
__device__ __forceinline__ float bperm(int addr, float v){
    return __int_as_float(__builtin_amdgcn_ds_bpermute(addr, __float_as_int(v)));
}

// ---------------------------------------------------------------------------
// Grid barrier with NO agent-scope fences (no L2 writeback/invalidate storm).
// All cross-block data moves through sc0/sc1 (coherent, L3-backed) accesses,
// so ordering only needs vmcnt drain: __threadfence_block (s_waitcnt, no
// cache ops). Arrival: relaxed agent atomics, hierarchical (8 lines).
// Poll: relaxed agent atomic LOAD (read-only). Fresh instance per barrier.
// ---------------------------------------------------------------------------
#define GBAR_STRIDE 160
#define GBAR_WORDS  (48 * GBAR_STRIDE)

__device__ __forceinline__ void gbar(unsigned* bar, int inst){
    __syncthreads();
    if (threadIdx.x == 0){
        __threadfence_block();               // s_waitcnt vmcnt(0): sc1 stores are at L3
        unsigned* ib = bar + inst * GBAR_STRIDE;
        unsigned sub = blockIdx.x & 7u;
        unsigned old = __hip_atomic_fetch_add(ib + sub * 16, 1u,
                          __ATOMIC_RELAXED, __HIP_MEMORY_SCOPE_AGENT);
        if (old == 63u){                     // last of my 64-block subgroup
            unsigned m = __hip_atomic_fetch_add(ib + 128, 1u,
                            __ATOMIC_RELAXED, __HIP_MEMORY_SCOPE_AGENT);
            if (m == 7u)                     // last subgroup overall
                __hip_atomic_store(ib + 144, 1u,
                                   __ATOMIC_RELAXED, __HIP_MEMORY_SCOPE_AGENT);
        }
        unsigned spins = 0;
        while (__hip_atomic_load(ib + 144, __ATOMIC_RELAXED,
                                 __HIP_MEMORY_SCOPE_AGENT) == 0u
               && spins < 300000u){          // bounded: no infinite hang
            __builtin_amdgcn_s_sleep(2);
            ++spins;
        }
        __threadfence_block();
    }
    __syncthreads();
}

// ---------------------------------------------------------------------------
// Encoder: bidirectional GRU, one wave per sequence. Unchanged from R2.
// grid 512 x 256.
// ---------------------------------------------------------------------------
__global__ __launch_bounds__(256, 2) void enc_kernel(
    const float* __restrict__ x,
    const float* __restrict__ emb_w, const float* __restrict__ emb_b,
    const float* __restrict__ wih_f, const float* __restrict__ whh_f,
    const float* __restrict__ bih_f, const float* __restrict__ bhh_f,
    const float* __restrict__ wih_b, const float* __restrict__ whh_b,
    const float* __restrict__ bih_b, const float* __restrict__ bhh_b,
    __hip_bfloat16* __restrict__ enc_outT, float* __restrict__ hT)
{
    int tid = threadIdx.x;
    int l = tid & 63;
    int wv = tid >> 6;
    int j = l & 31;
    int p = l >> 5;
    int S = blockIdx.x * 4 + wv;        // 0..2047
    int dir = S >> 10;
    int b = S & 1023;
    const float* wih = dir ? wih_b : wih_f;
    const float* whh = dir ? whh_b : whh_f;
    const float* bih = dir ? bih_b : bih_f;
    const float* bhh = dir ? bhh_b : bhh_f;

    float wr[8], wz[8], wn[8];
#pragma unroll
    for (int e = 0; e < 8; e++){
        int ee = 8 * p + e;
        wr[e] = wih[j * 16 + ee];
        wz[e] = wih[(32 + j) * 16 + ee];
        wn[e] = wih[(64 + j) * 16 + ee];
    }
    float ur[16], uz[16], un[16];
#pragma unroll
    for (int k = 0; k < 16; k++){
        int kk = 16 * p + k;
        ur[k] = whh[j * 32 + kk];
        uz[k] = whh[(32 + j) * 32 + kk];
        un[k] = whh[(64 + j) * 32 + kk];
    }
    float c_r  = p ? 0.f : (bih[j] + bhh[j]);
    float c_z  = p ? 0.f : (bih[32 + j] + bhh[32 + j]);
    float c_ni = p ? 0.f : bih[64 + j];
    float c_nh = p ? 0.f : bhh[64 + j];

    float ew[8];
#pragma unroll
    for (int f = 0; f < 8; f++) ew[f] = emb_w[(l & 15) * 8 + f];
    float ebias = emb_b[l & 15];

    int aE[8], aH[16];
#pragma unroll
    for (int i = 0; i < 8; i++) aE[i] = 4 * (8 * p + i);
#pragma unroll
    for (int i = 0; i < 16; i++) aH[i] = 4 * (16 * p + i);
    int aX = 4 * (l ^ 32);

    float h = 0.f;
    const float* xp = x + (size_t)b * 4096 + (dir ? 511 * 8 : 0);
    __hip_bfloat16* op = enc_outT + ((size_t)b * 512 + (dir ? 511 : 0)) * 64 + dir * 32 + j;
    int xstep = dir ? -8 : 8;
    ptrdiff_t ostep = dir ? -64 : 64;

    float4 cx0 = ((const float4*)xp)[0];
    float4 cx1 = ((const float4*)xp)[1];

    for (int it = 0; it < 512; ++it){
        const float* np = (it == 511) ? xp : (xp + xstep);
        float4 nx0 = ((const float4*)np)[0];
        float4 nx1 = ((const float4*)np)[1];

        float e0 = ebias;
        e0 = fmaf(cx0.x, ew[0], e0); e0 = fmaf(cx0.y, ew[1], e0);
        e0 = fmaf(cx0.z, ew[2], e0); e0 = fmaf(cx0.w, ew[3], e0);
        e0 = fmaf(cx1.x, ew[4], e0); e0 = fmaf(cx1.y, ew[5], e0);
        e0 = fmaf(cx1.z, ew[6], e0); e0 = fmaf(cx1.w, ew[7], e0);
        float me = fmaxf(e0, 0.f);

        float Ar = c_r, Az = c_z, Ani = c_ni, Anh = c_nh;
#pragma unroll
        for (int i = 0; i < 8; i++){
            float ev = bperm(aE[i], me);
            Ar = fmaf(ev, wr[i], Ar);
            Az = fmaf(ev, wz[i], Az);
            Ani = fmaf(ev, wn[i], Ani);
        }
#pragma unroll
        for (int i = 0; i < 16; i++){
            float hk = bperm(aH[i], h);
            Ar = fmaf(hk, ur[i], Ar);
            Az = fmaf(hk, uz[i], Az);
            Anh = fmaf(hk, un[i], Anh);
        }
        Ar  += bperm(aX, Ar);
        Az  += bperm(aX, Az);
        Ani += bperm(aX, Ani);
        Anh += bperm(aX, Anh);

        float r = fast_sigmoid(Ar);
        float z = fast_sigmoid(Az);
        float cand = fast_tanh(fmaf(r, Anh, Ani));
        h = (1.f - z) * cand + z * h;

        *op = __float2bfloat16(h);
        cx0 = nx0; cx1 = nx1;
        xp = np; op += ostep;
    }
    hT[b * 64 + dir * 32 + j] = h;
}

// ---------------------------------------------------------------------------
// s0 / sWs0 / dec_in0 init + zero barrier counters and per-step denominators.
// grid 128 x 256.
// ---------------------------------------------------------------------------
__global__ __launch_bounds__(256) void s0_kernel(
    const float* __restrict__ hT, const float* __restrict__ act_w, const float* __restrict__ act_b,
    const float* __restrict__ attn_w, const float* __restrict__ x,
    float* __restrict__ s, float* __restrict__ sWs, float* __restrict__ dec_in,
    unsigned* __restrict__ bar, float* __restrict__ denom24)
{
    if (blockIdx.x == 0){
        for (int i = threadIdx.x; i < GBAR_WORDS; i += 256) bar[i] = 0u;
        for (int i = threadIdx.x; i < 24 * 512; i += 256) denom24[i] = 0.f;
    }
    int j = threadIdx.x & 31, g = threadIdx.x >> 5;
    int b = blockIdx.x * 8 + g;
    float acc = act_b[j];
    const float4* aw = (const float4*)(act_w + j * 64);
    const float4* hp = (const float4*)(hT + b * 64);
#pragma unroll
    for (int c = 0; c < 16; c++){
        float4 wv = aw[c]; float4 hv = hp[c];
        acc = fmaf(hv.x, wv.x, acc); acc = fmaf(hv.y, wv.y, acc);
        acc = fmaf(hv.z, wv.z, acc); acc = fmaf(hv.w, wv.w, acc);
    }
    float s0v = fast_tanh(acc);
    s[b * 32 + j] = s0v;
    __shared__ float ssh[8][33];
    ssh[g][j] = s0v;
    __syncthreads();
    float a = 0.f;
    const float4* wsp = (const float4*)(attn_w + j * 96);   // Ws = attn_w[:, :32]
#pragma unroll
    for (int c = 0; c < 8; c++){
        float4 wv = wsp[c];
        a = fmaf(ssh[g][4 * c + 0], wv.x, a);
        a = fmaf(ssh[g][4 * c + 1], wv.y, a);
        a = fmaf(ssh[g][4 * c + 2], wv.z, a);
        a = fmaf(ssh[g][4 * c + 3], wv.w, a);
    }
    sWs[b * 32 + j] = a;
    if (j == 0) dec_in[b] = x[(size_t)b * 4096 + 511 * 8];
}

// ---------------------------------------------------------------------------
// enc_proj[t,b,j] = sum_d enc_outT[b,t,d] * We[j,d];  writes proj [t][b][32].
// grid 2048 x 256.
// ---------------------------------------------------------------------------
__global__ __launch_bounds__(256) void proj_kernel(
    const __hip_bfloat16* __restrict__ enc_outT, const float* __restrict__ attn_w,
    __hip_bfloat16* __restrict__ proj)
{
    int j = threadIdx.x & 31, g = threadIdx.x >> 5;
    float w[64];
    const float4* aw = (const float4*)(attn_w + j * 96 + 32);
#pragma unroll
    for (int c = 0; c < 16; c++){
        float4 q = aw[c];
        w[4 * c] = q.x; w[4 * c + 1] = q.y; w[4 * c + 2] = q.z; w[4 * c + 3] = q.w;
    }
    size_t base = (size_t)blockIdx.x * 256 + g * 32;
    for (int r = 0; r < 32; ++r){
        size_t pl = base + r;                      // pl = b*512 + t
        const uint4* ev = (const uint4*)(enc_outT + pl * 64);
        float acc = 0.f;
#pragma unroll
        for (int c = 0; c < 8; c++){
            uint4 pk = ev[c];
            acc = fmaf(bflo(pk.x), w[8 * c + 0], acc);
            acc = fmaf(bfhi(pk.x), w[8 * c + 1], acc);
            acc = fmaf(bflo(pk.y), w[8 * c + 2], acc);
            acc = fmaf(bfhi(pk.y), w[8 * c + 3], acc);
            acc = fmaf(bflo(pk.z), w[8 * c + 4], acc);
            acc = fmaf(bfhi(pk.z), w[8 * c + 5], acc);
            acc = fmaf(bflo(pk.w), w[8 * c + 6], acc);
            acc = fmaf(bfhi(pk.w), w[8 * c + 7], acc);
        }
        int t = (int)(pl & 511);
        int bb = (int)(pl >> 9);
        proj[((size_t)t * 1024 + bb) * 32 + j] = __float2bfloat16(acc);
    }
}

// ---------------------------------------------------------------------------
// Fused decoder, grid 512 x 256 (2 blocks/CU, co-resident).
// Cross-block arrays (sWs, Ebuf, denom) are accessed ONLY via volatile /
// relaxed-agent atomics (sc0/sc1 coherent, L3-backed). enc_outT/proj are
// read-only -> plain cacheable. s/dec_in are same-block -> plain.
// Per step:
//   Phase A: block g = (ttile = g>>4, btile = g&15): scores E[t,b] for a
//     16t x 64b tile; per-t wave reduce + fp32 atomicAdd into denom24[st].
//   gbar
//   Phase C: block g -> b in {g, g+512}: softmax weights, ctx (64KB
//     coalesced enc_outT[b]), GRU cell, fc, s/sWs/dec_in/out.
//   gbar
// ---------------------------------------------------------------------------
__global__ __launch_bounds__(256, 2) void dec_fused(
    const __hip_bfloat16* __restrict__ enc_outT, const __hip_bfloat16* __restrict__ proj,
    float* Ebuf, float* denom24,
    float* __restrict__ s, float* sWs, float* __restrict__ dec_in,
    const float* __restrict__ demb_w, const float* __restrict__ demb_b,
    const float* __restrict__ dwih, const float* __restrict__ dwhh,
    const float* __restrict__ dbih, const float* __restrict__ dbhh,
    const float* __restrict__ attn_w, const float* __restrict__ attn_v,
    const float* __restrict__ fc_w, const float* __restrict__ fc_b,
    float* __restrict__ out, unsigned* bar)
{
    int tid = threadIdx.x;
    int g = blockIdx.x;
    int wv = tid >> 6, l = tid & 63;

    __shared__ float w_sh[512];
    __shared__ float ctxp[4][64];
    __shared__ float rnn_sh[80];    // [embd(16), ctx(64)]
    __shared__ float scur[32];
    __shared__ float gsum[64];
    __shared__ float gin[32], ghn[32];
    __shared__ float snew[32];

    int t0 = (g >> 4) * 16;
    int b0 = (g & 15) * 64;
    int bA = b0 + l;                        // Phase-A batch element for this lane

    for (int st = 0; st < 24; ++st){
        float* denom = denom24 + st * 512;
        // ---------------- Phase A: 16t x 64b score tile ----------------
        {
            // sWs row for bA: coherent (written last step by other blocks)
            f4 sr[8];
            volatile const f4* sp = (volatile const f4*)(sWs + (size_t)bA * 32);
#pragma unroll
            for (int c = 0; c < 8; c++) sr[c] = sp[c];
#pragma unroll
            for (int k = 0; k < 4; k++){
                int t = t0 + wv * 4 + k;
                const uint4* pp = (const uint4*)(proj + ((size_t)t * 1024 + bA) * 32);
                float acc = 0.f;
#pragma unroll
                for (int c = 0; c < 4; c++){
                    uint4 pk = pp[c];
                    f4 s0v = sr[2 * c], s1v = sr[2 * c + 1];
                    acc = fmaf(attn_v[8 * c + 0], fast_tanh(s0v.x + bflo(pk.x)), acc);
                    acc = fmaf(attn_v[8 * c + 1], fast_tanh(s0v.y + bfhi(pk.x)), acc);
                    acc = fmaf(attn_v[8 * c + 2], fast_tanh(s0v.z + bflo(pk.y)), acc);
                    acc = fmaf(attn_v[8 * c + 3], fast_tanh(s0v.w + bfhi(pk.y)), acc);
                    acc = fmaf(attn_v[8 * c + 4], fast_tanh(s1v.x + bflo(pk.z)), acc);
                    acc = fmaf(attn_v[8 * c + 5], fast_tanh(s1v.y + bfhi(pk.z)), acc);
                    acc = fmaf(attn_v[8 * c + 6], fast_tanh(s1v.z + bflo(pk.w)), acc);
                    acc = fmaf(attn_v[8 * c + 7], fast_tanh(s1v.w + bfhi(pk.w)), acc);
                }
                float Ev = __builtin_amdgcn_exp2f(LOG2E * acc);   // |acc| <= ~3: safe
                ((volatile float*)Ebuf)[(size_t)t * 1024 + bA] = Ev;
                float part = Ev;
#pragma unroll
                for (int o = 32; o >= 1; o >>= 1) part += __shfl_xor(part, o, 64);
                if (l == 0) atomicAdd(denom + t, part);           // device-scope fp32
            }
        }
        gbar(bar, 2 * st);

        // ---------------- Phase C: ctx + GRU for b = g, g+512 ----------------
        float inv0 = __builtin_amdgcn_rcpf(((volatile const float*)denom)[tid]);
        float inv1 = __builtin_amdgcn_rcpf(((volatile const float*)denom)[tid + 256]);
        for (int bb = 0; bb < 2; ++bb){
            int b = g + bb * 512;
            __syncthreads();
            w_sh[tid] = ((volatile const float*)Ebuf)[(size_t)tid * 1024 + b] * inv0;
            w_sh[tid + 256] = ((volatile const float*)Ebuf)[(size_t)(tid + 256) * 1024 + b] * inv1;
            if (tid < 16) rnn_sh[tid] = fmaxf(fmaf(dec_in[b], demb_w[tid], demb_b[tid]), 0.f);
            if (tid >= 32 && tid < 64) scur[tid - 32] = s[b * 32 + tid - 32];
            __syncthreads();

            float acc0 = 0.f, acc1 = 0.f, acc2 = 0.f, acc3 = 0.f;
            float acc4 = 0.f, acc5 = 0.f, acc6 = 0.f, acc7 = 0.f;
            const uint4* ep = (const uint4*)(enc_outT + (size_t)b * 32768);
#pragma unroll
            for (int i = 0; i < 16; i++){
                int idx = i * 256 + tid;
                uint4 pk = ep[idx];
                float wgt = w_sh[idx >> 3];
                acc0 = fmaf(wgt, bflo(pk.x), acc0);
                acc1 = fmaf(wgt, bfhi(pk.x), acc1);
                acc2 = fmaf(wgt, bflo(pk.y), acc2);
                acc3 = fmaf(wgt, bfhi(pk.y), acc3);
                acc4 = fmaf(wgt, bflo(pk.z), acc4);
                acc5 = fmaf(wgt, bfhi(pk.z), acc5);
                acc6 = fmaf(wgt, bflo(pk.w), acc6);
                acc7 = fmaf(wgt, bfhi(pk.w), acc7);
            }
#pragma unroll
            for (int o = 8; o <= 32; o <<= 1){
                acc0 += __shfl_xor(acc0, o, 64); acc1 += __shfl_xor(acc1, o, 64);
                acc2 += __shfl_xor(acc2, o, 64); acc3 += __shfl_xor(acc3, o, 64);
                acc4 += __shfl_xor(acc4, o, 64); acc5 += __shfl_xor(acc5, o, 64);
                acc6 += __shfl_xor(acc6, o, 64); acc7 += __shfl_xor(acc7, o, 64);
            }
            if (l < 8){
                float* cp = &ctxp[wv][l * 8];
                cp[0] = acc0; cp[1] = acc1; cp[2] = acc2; cp[3] = acc3;
                cp[4] = acc4; cp[5] = acc5; cp[6] = acc6; cp[7] = acc7;
            }
            __syncthreads();
            if (tid < 64) rnn_sh[16 + tid] = ctxp[0][tid] + ctxp[1][tid] + ctxp[2][tid] + ctxp[3][tid];
            __syncthreads();

            if (tid < 96){
                int row = tid;
                float gi = dbih[row];
                const float4* wr = (const float4*)(dwih + row * 80);
#pragma unroll
                for (int c = 0; c < 20; c++){
                    float4 wv4 = wr[c];
                    gi = fmaf(rnn_sh[4 * c + 0], wv4.x, gi);
                    gi = fmaf(rnn_sh[4 * c + 1], wv4.y, gi);
                    gi = fmaf(rnn_sh[4 * c + 2], wv4.z, gi);
                    gi = fmaf(rnn_sh[4 * c + 3], wv4.w, gi);
                }
                float gh = dbhh[row];
                const float4* urow = (const float4*)(dwhh + row * 32);
#pragma unroll
                for (int c = 0; c < 8; c++){
                    float4 wv4 = urow[c];
                    gh = fmaf(scur[4 * c + 0], wv4.x, gh);
                    gh = fmaf(scur[4 * c + 1], wv4.y, gh);
                    gh = fmaf(scur[4 * c + 2], wv4.z, gh);
                    gh = fmaf(scur[4 * c + 3], wv4.w, gh);
                }
                if (row < 64) gsum[row] = gi + gh;
                else { gin[row - 64] = gi; ghn[row - 64] = gh; }
            }
            __syncthreads();

            if (tid < 32){
                float r = fast_sigmoid(gsum[tid]);
                float z = fast_sigmoid(gsum[32 + tid]);
                float cand = fast_tanh(fmaf(r, ghn[tid], gin[tid]));
                float sn = (1.f - z) * cand + z * scur[tid];
                snew[tid] = sn;
                s[b * 32 + tid] = sn;
            }
            __syncthreads();

            if (tid < 32){   // next-step sWs (coherent store: other blocks read it)
                float a = 0.f;
                const float4* aw = (const float4*)(attn_w + tid * 96);
#pragma unroll
                for (int c = 0; c < 8; c++){
                    float4 wv4 = aw[c];
                    a = fmaf(snew[4 * c + 0], wv4.x, a);
                    a = fmaf(snew[4 * c + 1], wv4.y, a);
                    a = fmaf(snew[4 * c + 2], wv4.z, a);
                    a = fmaf(snew[4 * c + 3], wv4.w, a);
                }
                ((volatile float*)sWs)[b * 32 + tid] = a;
            } else if (tid >= 64 && tid < 128){   // fc
                int ll = tid - 64;
                float cv0 = (ll < 32) ? snew[ll] : rnn_sh[ll - 16];
                float p = cv0 * fc_w[ll];
                if (ll < 48){
                    int i = 64 + ll;
                    float cv1 = (i < 96) ? rnn_sh[i - 16] : rnn_sh[i - 96];
                    p = fmaf(cv1, fc_w[i], p);
                }
#pragma unroll
                for (int o = 32; o >= 1; o >>= 1) p += __shfl_xor(p, o, 64);
                if (ll == 0){
                    float pred = p + fc_b[0];
                    out[b * 24 + st] = pred;
                    dec_in[b] = pred;
                }
            }
        }
        gbar(bar, 2 * st + 1);
    }
}

// ---------------------------------------------------------------------------
extern "C" void kernel_launch(void* const* d_in, const int* in_sizes, int n_in,
                              void* d_out, int out_size, void* d_ws, size_t ws_size,
                              hipStream_t stream)
{
    const float* x      = (const float*)d_in[0];
    const float* emb_w  = (const float*)d_in[2];
    const float* emb_b  = (const float*)d_in[3];
    const float* wih_f  = (const float*)d_in[4];
    const float* whh_f  = (const float*)d_in[5];
    const float* bih_f  = (const float*)d_in[6];
    const float* bhh_f  = (const float*)d_in[7];
    const float* wih_b  = (const float*)d_in[8];
    const float* whh_b  = (const float*)d_in[9];
    const float* bih_b  = (const float*)d_in[10];
    const float* bhh_b  = (const float*)d_in[11];
    const float* act_w  = (const float*)d_in[12];
    const float* act_b  = (const float*)d_in[13];
    const float* attn_w = (const float*)d_in[14];
    const float* attn_v = (const float*)d_in[15];
    const float* demb_w = (const float*)d_in[16];
    const float* demb_b = (const float*)d_in[17];
    const float* dwih   = (const float*)d_in[18];
    const float* dwhh   = (const float*)d_in[19];
    const float* dbih   = (const float*)d_in[20];
    const float* dbhh   = (const float*)d_in[21];
    const float* fc_w   = (const float*)d_in[22];
    const float* fc_b   = (const float*)d_in[23];
    (void)in_sizes; (void)n_in; (void)out_size; (void)ws_size;

    char* w = (char*)d_ws;
    __hip_bfloat16* enc_outT = (__hip_bfloat16*)w;                // [b][t][64] bf16, 67108864 B
    __hip_bfloat16* proj     = (__hip_bfloat16*)(w + 67108864);   // [t][b][32] bf16, 33554432 B
    float* hT      = (float*)(w + 100663296);                     // 1024*64*4
    float* s       = (float*)(w + 100925440);                     // 1024*32*4
    float* sWs     = (float*)(w + 101056512);                     // 1024*32*4
    float* Ebuf    = (float*)(w + 101187584);                     // [t][b] f32, 2097152 B
    float* denom24 = (float*)(w + 103284736);                     // 24*512*4 = 49152 B
    float* dec_in  = (float*)(w + 103333888);                     // 1024*4
    unsigned* bar  = (unsigned*)(w + 103337984);                  // 48*160*4 = 30720 B
    float* out = (float*)d_out;

    enc_kernel<<<512, 256, 0, stream>>>(x, emb_w, emb_b, wih_f, whh_f, bih_f, bhh_f,
                                        wih_b, whh_b, bih_b, bhh_b, enc_outT, hT);
    s0_kernel<<<128, 256, 0, stream>>>(hT, act_w, act_b, attn_w, x, s, sWs, dec_in,
                                       bar, denom24);
    proj_kernel<<<2048, 256, 0, stream>>>(enc_outT, attn_w, proj);
    dec_fused<<<512, 256, 0, stream>>>(enc_outT, proj, Ebuf, denom24, s, sWs, dec_in,
                                       demb_w, demb_b, dwih, dwhh, dbih, dbhh,
                                       attn_w, attn_v, fc_w, fc_b, out, bar);
}

// Round 7
// 1473.958 us; speedup vs baseline: 2.9349x; 1.0338x over previous
//
#include <hip/hip_runtime.h>
#include <hip/hip_bf16.h>
#include <stdint.h>
#include <stddef.h>

// Problem dims: B=1024, T=512, F=8, E=16, H=32, O=1, TO=24

#define LOG2E 1.44269504088896340736f

__device__ __forceinline__ float fast_sigmoid(float x){
    return __builtin_amdgcn_rcpf(1.f + __builtin_amdgcn_exp2f(-LOG2E * x));
}
__device__ __forceinline__ float fast_tanh(float x){
    return 1.f - 2.f * __builtin_amdgcn_rcpf(1.f + __builtin_amdgcn_exp2f(2.f * LOG2E * x));
}
__device__ __forceinline__ float bflo(unsigned u){ return __uint_as_float(u << 16); }
__device__ __forceinline__ float bfhi(unsigned u){ return __uint_as_float(u & 0xffff0000u); }
__device__ __forceinline__ float bperm(int addr, float v){
    return __int_as_float(__builtin_amdgcn_ds_bpermute(addr, __float_as_int(v)));
}
__device__ __forceinline__ unsigned bpermu(int addr, unsigned v){
    return (unsigned)__builtin_amdgcn_ds_bpermute(addr, (int)v);
}
// pack (lo,hi) fp32 -> bf16x2 word
__device__ __forceinline__ unsigned pack2bf(float lo, float hi){
    union { __hip_bfloat162 b; unsigned u; } cv;
    cv.b = __float22bfloat162_rn(make_float2(lo, hi));
    return cv.u;
}

// ---------------------------------------------------------------------------
// Grid barrier, no agent-scope fences (R6-validated). Cross-block data moves
// via sc0/volatile (L3 coherence point); barrier only needs vmcnt drain.
// ---------------------------------------------------------------------------
#define GBAR_STRIDE 160
#define GBAR_WORDS  (48 * GBAR_STRIDE)

__device__ __forceinline__ void gbar(unsigned* bar, int inst){
    __syncthreads();
    if (threadIdx.x == 0){
        __threadfence_block();
        unsigned* ib = bar + inst * GBAR_STRIDE;
        unsigned sub = blockIdx.x & 7u;
        unsigned old = __hip_atomic_fetch_add(ib + sub * 16, 1u,
                          __ATOMIC_RELAXED, __HIP_MEMORY_SCOPE_AGENT);
        if (old == 63u){
            unsigned m = __hip_atomic_fetch_add(ib + 128, 1u,
                            __ATOMIC_RELAXED, __HIP_MEMORY_SCOPE_AGENT);
            if (m == 7u)
                __hip_atomic_store(ib + 144, 1u,
                                   __ATOMIC_RELAXED, __HIP_MEMORY_SCOPE_AGENT);
        }
        unsigned spins = 0;
        while (__hip_atomic_load(ib + 144, __ATOMIC_RELAXED,
                                 __HIP_MEMORY_SCOPE_AGENT) == 0u
               && spins < 300000u){
            __builtin_amdgcn_s_sleep(2);
            ++spins;
        }
        __threadfence_block();
    }
    __syncthreads();
}

// ---------------------------------------------------------------------------
// Encoder: bidirectional GRU, one wave per sequence (64 lanes; lane=(j,K-half)).
// R7: broadcasts packed as bf16x2 -> DS ops/iter 28 -> 18 (1 swz + 4 bperm emb,
// 1 swz + 8 bperm h, 4 fp32 combines). h state & combines stay fp32.
// grid 512 x 256.
// ---------------------------------------------------------------------------
__global__ __launch_bounds__(256, 2) void enc_kernel(
    const float* __restrict__ x,
    const float* __restrict__ emb_w, const float* __restrict__ emb_b,
    const float* __restrict__ wih_f, const float* __restrict__ whh_f,
    const float* __restrict__ bih_f, const float* __restrict__ bhh_f,
    const float* __restrict__ wih_b, const float* __restrict__ whh_b,
    const float* __restrict__ bih_b, const float* __restrict__ bhh_b,
    __hip_bfloat16* __restrict__ enc_outT, float* __restrict__ hT)
{
    int tid = threadIdx.x;
    int l = tid & 63;
    int wv = tid >> 6;
    int j = l & 31;
    int p = l >> 5;
    int S = blockIdx.x * 4 + wv;        // 0..2047
    int dir = S >> 10;
    int b = S & 1023;
    const float* wih = dir ? wih_b : wih_f;
    const float* whh = dir ? whh_b : whh_f;
    const float* bih = dir ? bih_b : bih_f;
    const float* bhh = dir ? bhh_b : bhh_f;

    float wr[8], wz[8], wn[8];
#pragma unroll
    for (int e = 0; e < 8; e++){
        int ee = 8 * p + e;
        wr[e] = wih[j * 16 + ee];
        wz[e] = wih[(32 + j) * 16 + ee];
        wn[e] = wih[(64 + j) * 16 + ee];
    }
    float ur[16], uz[16], un[16];
#pragma unroll
    for (int k = 0; k < 16; k++){
        int kk = 16 * p + k;
        ur[k] = whh[j * 32 + kk];
        uz[k] = whh[(32 + j) * 32 + kk];
        un[k] = whh[(64 + j) * 32 + kk];
    }
    float c_r  = p ? 0.f : (bih[j] + bhh[j]);
    float c_z  = p ? 0.f : (bih[32 + j] + bhh[32 + j]);
    float c_ni = p ? 0.f : bih[64 + j];
    float c_nh = p ? 0.f : bhh[64 + j];

    float ew[8];
#pragma unroll
    for (int f = 0; f < 8; f++) ew[f] = emb_w[(l & 15) * 8 + f];
    float ebias = emb_b[l & 15];

    // packed-broadcast addresses: pair sources are even lanes
    int aE2[4], aH2[8];
#pragma unroll
    for (int i = 0; i < 4; i++) aE2[i] = 4 * (8 * p + 2 * i);
#pragma unroll
    for (int i = 0; i < 8; i++) aH2[i] = 4 * (16 * p + 2 * i);
    int aX = 4 * (l ^ 32);
    int odd = l & 1;

    float h = 0.f;
    const float* xp = x + (size_t)b * 4096 + (dir ? 511 * 8 : 0);
    __hip_bfloat16* op = enc_outT + ((size_t)b * 512 + (dir ? 511 : 0)) * 64 + dir * 32 + j;
    int xstep = dir ? -8 : 8;
    ptrdiff_t ostep = dir ? -64 : 64;

    float4 cx0 = ((const float4*)xp)[0];
    float4 cx1 = ((const float4*)xp)[1];

    for (int it = 0; it < 512; ++it){
        const float* np = (it == 511) ? xp : (xp + xstep);
        float4 nx0 = ((const float4*)np)[0];
        float4 nx1 = ((const float4*)np)[1];

        float e0 = ebias;
        e0 = fmaf(cx0.x, ew[0], e0); e0 = fmaf(cx0.y, ew[1], e0);
        e0 = fmaf(cx0.z, ew[2], e0); e0 = fmaf(cx0.w, ew[3], e0);
        e0 = fmaf(cx1.x, ew[4], e0); e0 = fmaf(cx1.y, ew[5], e0);
        e0 = fmaf(cx1.z, ew[6], e0); e0 = fmaf(cx1.w, ew[7], e0);
        float me = fmaxf(e0, 0.f);          // lane holds emb[l&15]

        // pack neighbor pairs (bf16x2); even lane 2m ends with (v_2m, v_2m+1)
        float en = __shfl_xor(me, 1, 64);
        unsigned pkE = pack2bf(odd ? en : me, odd ? me : en);
        float hn = __shfl_xor(h, 1, 64);
        unsigned pkH = pack2bf(odd ? hn : h, odd ? h : hn);

        float Ar = c_r, Az = c_z, Ani = c_ni, Anh = c_nh;
#pragma unroll
        for (int i = 0; i < 4; i++){
            unsigned u = bpermu(aE2[i], pkE);
            float elo = bflo(u), ehi = bfhi(u);
            Ar = fmaf(elo, wr[2 * i], Ar);      Ar = fmaf(ehi, wr[2 * i + 1], Ar);
            Az = fmaf(elo, wz[2 * i], Az);      Az = fmaf(ehi, wz[2 * i + 1], Az);
            Ani = fmaf(elo, wn[2 * i], Ani);    Ani = fmaf(ehi, wn[2 * i + 1], Ani);
        }
#pragma unroll
        for (int i = 0; i < 8; i++){
            unsigned u = bpermu(aH2[i], pkH);
            float hlo = bflo(u), hhi = bfhi(u);
            Ar = fmaf(hlo, ur[2 * i], Ar);      Ar = fmaf(hhi, ur[2 * i + 1], Ar);
            Az = fmaf(hlo, uz[2 * i], Az);      Az = fmaf(hhi, uz[2 * i + 1], Az);
            Anh = fmaf(hlo, un[2 * i], Anh);    Anh = fmaf(hhi, un[2 * i + 1], Anh);
        }
        // combine halves (fp32)
        Ar  += bperm(aX, Ar);
        Az  += bperm(aX, Az);
        Ani += bperm(aX, Ani);
        Anh += bperm(aX, Anh);

        float r = fast_sigmoid(Ar);
        float z = fast_sigmoid(Az);
        float cand = fast_tanh(fmaf(r, Anh, Ani));
        h = (1.f - z) * cand + z * h;

        *op = __float2bfloat16(h);
        cx0 = nx0; cx1 = nx1;
        xp = np; op += ostep;
    }
    hT[b * 64 + dir * 32 + j] = h;
}

// ---------------------------------------------------------------------------
// s0 / sWs0 / dec_in0 init + zero barrier counters and padded denominators.
// grid 128 x 256.
// ---------------------------------------------------------------------------
__global__ __launch_bounds__(256) void s0_kernel(
    const float* __restrict__ hT, const float* __restrict__ act_w, const float* __restrict__ act_b,
    const float* __restrict__ attn_w, const float* __restrict__ x,
    float* __restrict__ s, float* __restrict__ sWs, float* __restrict__ dec_in,
    unsigned* __restrict__ bar, float* __restrict__ denomP)
{
    if (blockIdx.x == 0){
        for (int i = threadIdx.x; i < GBAR_WORDS; i += 256) bar[i] = 0u;
    }
    {   // zero 24*512*16 padded denom words, spread over 128 blocks
        int base = blockIdx.x * 1536;
        for (int i = threadIdx.x; i < 1536; i += 256) denomP[base + i] = 0.f;
    }
    int j = threadIdx.x & 31, g = threadIdx.x >> 5;
    int b = blockIdx.x * 8 + g;
    float acc = act_b[j];
    const float4* aw = (const float4*)(act_w + j * 64);
    const float4* hp = (const float4*)(hT + b * 64);
#pragma unroll
    for (int c = 0; c < 16; c++){
        float4 wv = aw[c]; float4 hv = hp[c];
        acc = fmaf(hv.x, wv.x, acc); acc = fmaf(hv.y, wv.y, acc);
        acc = fmaf(hv.z, wv.z, acc); acc = fmaf(hv.w, wv.w, acc);
    }
    float s0v = fast_tanh(acc);
    s[b * 32 + j] = s0v;
    __shared__ float ssh[8][33];
    ssh[g][j] = s0v;
    __syncthreads();
    float a = 0.f;
    const float4* wsp = (const float4*)(attn_w + j * 96);   // Ws = attn_w[:, :32]
#pragma unroll
    for (int c = 0; c < 8; c++){
        float4 wv = wsp[c];
        a = fmaf(ssh[g][4 * c + 0], wv.x, a);
        a = fmaf(ssh[g][4 * c + 1], wv.y, a);
        a = fmaf(ssh[g][4 * c + 2], wv.z, a);
        a = fmaf(ssh[g][4 * c + 3], wv.w, a);
    }
    sWs[b * 32 + j] = a;
    if (j == 0) dec_in[b] = x[(size_t)b * 4096 + 511 * 8];
}

// ---------------------------------------------------------------------------
// projT[b,t,j] = sum_d enc_outT[b,t,d] * We[j,d];  [b][t][32] layout (column-
// contiguous for the per-b decoder blocks). grid 2048 x 256.
// ---------------------------------------------------------------------------
__global__ __launch_bounds__(256) void proj_kernel(
    const __hip_bfloat16* __restrict__ enc_outT, const float* __restrict__ attn_w,
    __hip_bfloat16* __restrict__ projT)
{
    int j = threadIdx.x & 31, g = threadIdx.x >> 5;
    float w[64];
    const float4* aw = (const float4*)(attn_w + j * 96 + 32);
#pragma unroll
    for (int c = 0; c < 16; c++){
        float4 q = aw[c];
        w[4 * c] = q.x; w[4 * c + 1] = q.y; w[4 * c + 2] = q.z; w[4 * c + 3] = q.w;
    }
    size_t base = (size_t)blockIdx.x * 256 + g * 32;
    for (int r = 0; r < 32; ++r){
        size_t pl = base + r;                      // pl = b*512 + t
        const uint4* ev = (const uint4*)(enc_outT + pl * 64);
        float acc = 0.f;
#pragma unroll
        for (int c = 0; c < 8; c++){
            uint4 pk = ev[c];
            acc = fmaf(bflo(pk.x), w[8 * c + 0], acc);
            acc = fmaf(bfhi(pk.x), w[8 * c + 1], acc);
            acc = fmaf(bflo(pk.y), w[8 * c + 2], acc);
            acc = fmaf(bfhi(pk.y), w[8 * c + 3], acc);
            acc = fmaf(bflo(pk.z), w[8 * c + 4], acc);
            acc = fmaf(bfhi(pk.z), w[8 * c + 5], acc);
            acc = fmaf(bflo(pk.w), w[8 * c + 6], acc);
            acc = fmaf(bfhi(pk.w), w[8 * c + 7], acc);
        }
        projT[pl * 32 + j] = __float2bfloat16(acc);
    }
}

// ---------------------------------------------------------------------------
// Fused decoder v3: grid 512 x 256 (2 blocks/CU).  Block g owns b = {g, g+512}
// for BOTH score and ctx phases: its projT columns (64 KB) are LDS-cached ONCE
// and reused for all 24 steps; E values live in LDS (never in HBM).  Only the
// per-t batch-softmax denominators cross blocks: padded fp32 atomicAdd lines.
// Per step:
//   Phase A: scores E[t,b] for own 2 b-columns from LDS; atomicAdd partials
//            into denomP[st][t] (one 64B line per t).     gbar
//   Phase C: invden from denomP; weights = E_sh*invden; ctx = 64KB coalesced
//            enc_outT[b] sweep; GRU; fc; sWs (volatile).  gbar
// ---------------------------------------------------------------------------
__global__ __launch_bounds__(256, 2) void dec_fused(
    const __hip_bfloat16* __restrict__ enc_outT, const __hip_bfloat16* __restrict__ projT,
    float* denomP,
    float* __restrict__ s, float* sWs, float* __restrict__ dec_in,
    const float* __restrict__ demb_w, const float* __restrict__ demb_b,
    const float* __restrict__ dwih, const float* __restrict__ dwhh,
    const float* __restrict__ dbih, const float* __restrict__ dbhh,
    const float* __restrict__ attn_w, const float* __restrict__ attn_v,
    const float* __restrict__ fc_w, const float* __restrict__ fc_b,
    float* __restrict__ out, unsigned* bar)
{
    int tid = threadIdx.x;
    int g = blockIdx.x;
    int wv = tid >> 6, l = tid & 63;

    __shared__ uint4 proj_sh4[4096];          // 2 cols x 512 t x 32 j bf16 = 64 KB
    __shared__ float E_sh[1024];              // [bb][t]
    __shared__ float invden_sh[512];
    __shared__ __align__(16) float sWs_sh[64];
    __shared__ float ctxp[4][64];
    __shared__ float rnn_sh[80];              // [embd(16), ctx(64)]
    __shared__ float scur[32];
    __shared__ float gsum[64];
    __shared__ float gin[32], ghn[32];
    __shared__ float snew[32];

    // ---- one-time: cache projT columns for b=g and b=g+512 (64 KB) ----
    {
        const uint4* p0 = (const uint4*)(projT + (size_t)g * 16384);
        const uint4* p1 = (const uint4*)(projT + (size_t)(g + 512) * 16384);
#pragma unroll
        for (int i = 0; i < 8; i++) proj_sh4[i * 256 + tid] = p0[i * 256 + tid];
#pragma unroll
        for (int i = 0; i < 8; i++) proj_sh4[2048 + i * 256 + tid] = p1[i * 256 + tid];
    }
    float av[32];
    {
        const float4* vv = (const float4*)attn_v;
#pragma unroll
        for (int c = 0; c < 8; c++){
            float4 q = vv[c];
            av[4 * c] = q.x; av[4 * c + 1] = q.y; av[4 * c + 2] = q.z; av[4 * c + 3] = q.w;
        }
    }
    __syncthreads();

    for (int st = 0; st < 24; ++st){
        float* denom = denomP + st * 512 * 16;
        // ---------------- Phase A: own-column scores ----------------
        if (tid < 64){   // load sWs rows for b=g, g+512 (coherent)
            int bb = tid >> 5, jj = tid & 31;
            sWs_sh[tid] = ((volatile const float*)sWs)[(g + bb * 512) * 32 + jj];
        }
        __syncthreads();
        float part0 = 0.f, part1 = 0.f;   // partials for t=tid, t=tid+256
#pragma unroll
        for (int bb = 0; bb < 2; ++bb){
            float4 sw[8];
            const float4* swp = (const float4*)(sWs_sh + bb * 32);
#pragma unroll
            for (int c = 0; c < 8; c++) sw[c] = swp[c];
#pragma unroll
            for (int k = 0; k < 2; ++k){
                int t = tid + k * 256;
                const uint4* pr = proj_sh4 + (bb * 512 + t) * 4;
                float acc = 0.f;
#pragma unroll
                for (int c = 0; c < 4; c++){
                    uint4 pk = pr[c];
                    float4 s0v = sw[2 * c], s1v = sw[2 * c + 1];
                    acc = fmaf(av[8 * c + 0], fast_tanh(s0v.x + bflo(pk.x)), acc);
                    acc = fmaf(av[8 * c + 1], fast_tanh(s0v.y + bfhi(pk.x)), acc);
                    acc = fmaf(av[8 * c + 2], fast_tanh(s0v.z + bflo(pk.y)), acc);
                    acc = fmaf(av[8 * c + 3], fast_tanh(s0v.w + bfhi(pk.y)), acc);
                    acc = fmaf(av[8 * c + 4], fast_tanh(s1v.x + bflo(pk.z)), acc);
                    acc = fmaf(av[8 * c + 5], fast_tanh(s1v.y + bfhi(pk.z)), acc);
                    acc = fmaf(av[8 * c + 6], fast_tanh(s1v.z + bflo(pk.w)), acc);
                    acc = fmaf(av[8 * c + 7], fast_tanh(s1v.w + bfhi(pk.w)), acc);
                }
                float Ev = __builtin_amdgcn_exp2f(LOG2E * acc);   // |acc|<=~3: safe
                E_sh[bb * 512 + t] = Ev;
                if (k == 0) part0 += Ev; else part1 += Ev;
            }
        }
        atomicAdd(denom + (size_t)tid * 16, part0);
        atomicAdd(denom + (size_t)(tid + 256) * 16, part1);
        gbar(bar, 2 * st);

        // ---------------- Phase C: ctx + GRU for b = g, g+512 ----------------
        invden_sh[tid] = __builtin_amdgcn_rcpf(((volatile const float*)denom)[(size_t)tid * 16]);
        invden_sh[tid + 256] = __builtin_amdgcn_rcpf(((volatile const float*)denom)[(size_t)(tid + 256) * 16]);
        for (int bb = 0; bb < 2; ++bb){
            int b = g + bb * 512;
            __syncthreads();
            if (tid < 16) rnn_sh[tid] = fmaxf(fmaf(dec_in[b], demb_w[tid], demb_b[tid]), 0.f);
            if (tid >= 32 && tid < 64) scur[tid - 32] = s[b * 32 + tid - 32];
            __syncthreads();

            float acc0 = 0.f, acc1 = 0.f, acc2 = 0.f, acc3 = 0.f;
            float acc4 = 0.f, acc5 = 0.f, acc6 = 0.f, acc7 = 0.f;
            const uint4* ep = (const uint4*)(enc_outT + (size_t)b * 32768);
#pragma unroll
            for (int i = 0; i < 16; i++){
                int idx = i * 256 + tid;
                uint4 pk = ep[idx];
                int t = idx >> 3;
                float wgt = E_sh[bb * 512 + t] * invden_sh[t];
                acc0 = fmaf(wgt, bflo(pk.x), acc0);
                acc1 = fmaf(wgt, bfhi(pk.x), acc1);
                acc2 = fmaf(wgt, bflo(pk.y), acc2);
                acc3 = fmaf(wgt, bfhi(pk.y), acc3);
                acc4 = fmaf(wgt, bflo(pk.z), acc4);
                acc5 = fmaf(wgt, bfhi(pk.z), acc5);
                acc6 = fmaf(wgt, bflo(pk.w), acc6);
                acc7 = fmaf(wgt, bfhi(pk.w), acc7);
            }
#pragma unroll
            for (int o = 8; o <= 32; o <<= 1){
                acc0 += __shfl_xor(acc0, o, 64); acc1 += __shfl_xor(acc1, o, 64);
                acc2 += __shfl_xor(acc2, o, 64); acc3 += __shfl_xor(acc3, o, 64);
                acc4 += __shfl_xor(acc4, o, 64); acc5 += __shfl_xor(acc5, o, 64);
                acc6 += __shfl_xor(acc6, o, 64); acc7 += __shfl_xor(acc7, o, 64);
            }
            if (l < 8){
                float* cp = &ctxp[wv][l * 8];
                cp[0] = acc0; cp[1] = acc1; cp[2] = acc2; cp[3] = acc3;
                cp[4] = acc4; cp[5] = acc5; cp[6] = acc6; cp[7] = acc7;
            }
            __syncthreads();
            if (tid < 64) rnn_sh[16 + tid] = ctxp[0][tid] + ctxp[1][tid] + ctxp[2][tid] + ctxp[3][tid];
            __syncthreads();

            if (tid < 96){
                int row = tid;
                float gi = dbih[row];
                const float4* wr = (const float4*)(dwih + row * 80);
#pragma unroll
                for (int c = 0; c < 20; c++){
                    float4 wv4 = wr[c];
                    gi = fmaf(rnn_sh[4 * c + 0], wv4.x, gi);
                    gi = fmaf(rnn_sh[4 * c + 1], wv4.y, gi);
                    gi = fmaf(rnn_sh[4 * c + 2], wv4.z, gi);
                    gi = fmaf(rnn_sh[4 * c + 3], wv4.w, gi);
                }
                float gh = dbhh[row];
                const float4* urow = (const float4*)(dwhh + row * 32);
#pragma unroll
                for (int c = 0; c < 8; c++){
                    float4 wv4 = urow[c];
                    gh = fmaf(scur[4 * c + 0], wv4.x, gh);
                    gh = fmaf(scur[4 * c + 1], wv4.y, gh);
                    gh = fmaf(scur[4 * c + 2], wv4.z, gh);
                    gh = fmaf(scur[4 * c + 3], wv4.w, gh);
                }
                if (row < 64) gsum[row] = gi + gh;
                else { gin[row - 64] = gi; ghn[row - 64] = gh; }
            }
            __syncthreads();

            if (tid < 32){
                float r = fast_sigmoid(gsum[tid]);
                float z = fast_sigmoid(gsum[32 + tid]);
                float cand = fast_tanh(fmaf(r, ghn[tid], gin[tid]));
                float sn = (1.f - z) * cand + z * scur[tid];
                snew[tid] = sn;
                s[b * 32 + tid] = sn;
            }
            __syncthreads();

            if (tid < 32){   // next-step sWs (coherent store)
                float a = 0.f;
                const float4* aw = (const float4*)(attn_w + tid * 96);
#pragma unroll
                for (int c = 0; c < 8; c++){
                    float4 wv4 = aw[c];
                    a = fmaf(snew[4 * c + 0], wv4.x, a);
                    a = fmaf(snew[4 * c + 1], wv4.y, a);
                    a = fmaf(snew[4 * c + 2], wv4.z, a);
                    a = fmaf(snew[4 * c + 3], wv4.w, a);
                }
                ((volatile float*)sWs)[b * 32 + tid] = a;
            } else if (tid >= 64 && tid < 128){   // fc
                int ll = tid - 64;
                float cv0 = (ll < 32) ? snew[ll] : rnn_sh[ll - 16];
                float p = cv0 * fc_w[ll];
                if (ll < 48){
                    int i = 64 + ll;
                    float cv1 = (i < 96) ? rnn_sh[i - 16] : rnn_sh[i - 96];
                    p = fmaf(cv1, fc_w[i], p);
                }
#pragma unroll
                for (int o = 32; o >= 1; o >>= 1) p += __shfl_xor(p, o, 64);
                if (ll == 0){
                    float pred = p + fc_b[0];
                    out[b * 24 + st] = pred;
                    dec_in[b] = pred;
                }
            }
        }
        gbar(bar, 2 * st + 1);
    }
}

// ---------------------------------------------------------------------------
extern "C" void kernel_launch(void* const* d_in, const int* in_sizes, int n_in,
                              void* d_out, int out_size, void* d_ws, size_t ws_size,
                              hipStream_t stream)
{
    const float* x      = (const float*)d_in[0];
    const float* emb_w  = (const float*)d_in[2];
    const float* emb_b  = (const float*)d_in[3];
    const float* wih_f  = (const float*)d_in[4];
    const float* whh_f  = (const float*)d_in[5];
    const float* bih_f  = (const float*)d_in[6];
    const float* bhh_f  = (const float*)d_in[7];
    const float* wih_b  = (const float*)d_in[8];
    const float* whh_b  = (const float*)d_in[9];
    const float* bih_b  = (const float*)d_in[10];
    const float* bhh_b  = (const float*)d_in[11];
    const float* act_w  = (const float*)d_in[12];
    const float* act_b  = (const float*)d_in[13];
    const float* attn_w = (const float*)d_in[14];
    const float* attn_v = (const float*)d_in[15];
    const float* demb_w = (const float*)d_in[16];
    const float* demb_b = (const float*)d_in[17];
    const float* dwih   = (const float*)d_in[18];
    const float* dwhh   = (const float*)d_in[19];
    const float* dbih   = (const float*)d_in[20];
    const float* dbhh   = (const float*)d_in[21];
    const float* fc_w   = (const float*)d_in[22];
    const float* fc_b   = (const float*)d_in[23];
    (void)in_sizes; (void)n_in; (void)out_size; (void)ws_size;

    char* w = (char*)d_ws;
    __hip_bfloat16* enc_outT = (__hip_bfloat16*)w;                // [b][t][64] bf16, 67108864 B
    __hip_bfloat16* projT    = (__hip_bfloat16*)(w + 67108864);   // [b][t][32] bf16, 33554432 B
    float* hT      = (float*)(w + 100663296);                     // 1024*64*4  -> 100925440
    float* s       = (float*)(w + 100925440);                     // 1024*32*4  -> 101056512
    float* sWs     = (float*)(w + 101056512);                     // 1024*32*4  -> 101187584
    float* denomP  = (float*)(w + 101187584);                     // 24*512*16*4 = 786432 -> 101974016
    float* dec_in  = (float*)(w + 101974016);                     // 1024*4 -> 101978112
    unsigned* bar  = (unsigned*)(w + 101978112);                  // 48*160*4 = 30720
    float* out = (float*)d_out;

    enc_kernel<<<512, 256, 0, stream>>>(x, emb_w, emb_b, wih_f, whh_f, bih_f, bhh_f,
                                        wih_b, whh_b, bih_b, bhh_b, enc_outT, hT);
    s0_kernel<<<128, 256, 0, stream>>>(hT, act_w, act_b, attn_w, x, s, sWs, dec_in,
                                       bar, denomP);
    proj_kernel<<<2048, 256, 0, stream>>>(enc_outT, attn_w, projT);
    dec_fused<<<512, 256, 0, stream>>>(enc_outT, projT, denomP, s, sWs, dec_in,
                                       demb_w, demb_b, dwih, dwhh, dbih, dbhh,
                                       attn_w, attn_v, fc_w, fc_b, out, bar);
}